// Round 4
// baseline (2711.369 us; speedup 1.0000x reference)
//
#include <hip/hip_runtime.h>

// VectorQuantiser forward, MI355X fp32.
// N=65536 tokens (16x64x64, channel stride 4096), K=1024 codes, D=64.
//
// Round 4: R2/R3 counters showed k_scores stuck at VALUBusy~40% regardless of
// z-residency tricks -> the real wall is the e-operand SGPR stream: 64 SGPRs
// per code can't double-buffer (SGPR file ~102), so every code serializes a
// full SMEM round-trip (~400 cyc). Structural swap: lane=code, e flows per-lane
// through VGPRs (coalesced dwordx4, vmcnt-pipelined); z becomes the wave-
// uniform SGPR operand (16-token tile, 64 floats per j-quad, shared by all
// waves -> scalar-L1 reuse); accumulators 16x4=64 VGPR (not demotable).
// ALL rounding-sensitive fp orders bit-identical to the passing R2/R3 code:
// chain m = d{m,m+4,...,m+60} ascending, (c0+c1)+(c2+c3), same compose,
// same tie-break keys. nzn2/en2 precomputed with the identical pairwise fn.

// ---- ws layout (bytes) ----
#define WS_ROW   0        // u64 wsrow[65536]  packed (ord(d)<<32)|~k
#define WS_COL   524288   // u64 wscol[1024]   packed (ord(d)<<32)|~n
#define WS_CNT   532480   // u32 counts[1024]
#define WS_LOSS  536576   // double loss_acc
#define WS_EN2   536592   // float en2[1024]
#define WS_NZN2  540688   // float nzn2[65536] (negated ||z||^2)
#define WS_EQ    802832   // float eq[16][1024][4]  e quad-major
#define WS_CLEAR 536592   // memset region: row/col/cnt/loss
#define WS_BYTES (WS_EQ + 262144)

__device__ __forceinline__ unsigned int f32_ord(float x) {
    unsigned int b = __float_as_uint(x);
    return (b & 0x80000000u) ? ~b : (b | 0x80000000u);
}

// numpy pairwise sum of squares over 64 values (8 strided chains, then
// ((r0+r1)+(r2+r3))+((r4+r5)+(r6+r7))), fp32 per-op, no contraction. FROZEN.
template <typename F>
__device__ __forceinline__ float np_pairwise64_sq(F get) {
    float r[8];
#pragma unroll
    for (int j = 0; j < 8; ++j) {
        float v = get(j);
        r[j] = __fmul_rn(v, v);
    }
#pragma unroll
    for (int i = 8; i < 64; i += 8) {
#pragma unroll
        for (int j = 0; j < 8; ++j) {
            float v = get(i + j);
            r[j] = __fadd_rn(r[j], __fmul_rn(v, v));
        }
    }
    return __fadd_rn(__fadd_rn(__fadd_rn(r[0], r[1]), __fadd_rn(r[2], r[3])),
                     __fadd_rn(__fadd_rn(r[4], r[5]), __fadd_rn(r[6], r[7])));
}

// ---- K_prep: blocks 0..255 nzn2[65536]; 256..259 en2[1024]; 260..263 eq ----
__global__ __launch_bounds__(256) void k_prep(const float* __restrict__ z,
                                              const float* __restrict__ emb,
                                              float* __restrict__ nzn2,
                                              float* __restrict__ en2,
                                              float* __restrict__ eq) {
    const int bx = blockIdx.x;
    const int t  = threadIdx.x;
    if (bx < 256) {
        // nzn2: thread = token, strided reads are lane-coalesced (hw contiguous)
        const int n  = bx * 256 + t;
        const int b  = n >> 12;
        const int hw = n & 4095;
        const float* zp = z + (size_t)b * 262144 + hw;
        nzn2[n] = -np_pairwise64_sq([&](int i) { return zp[(size_t)i * 4096]; });
    } else if (bx < 260) {
        const int k = (bx - 256) * 256 + t;
        const float* a = emb + (size_t)k * 64;
        en2[k] = np_pairwise64_sq([&](int i) { return a[i]; });
    } else {
        // eq[j][code] = emb[code][4j..4j+3]  (quad-major for coalesced k_scores)
        const int code = (bx - 260) * 256 + t;
        const float4* e4 = reinterpret_cast<const float4*>(emb) + (size_t)code * 16;
        float4* q4 = reinterpret_cast<float4*>(eq);
#pragma unroll
        for (int j = 0; j < 16; ++j)
            q4[(size_t)j * 1024 + code] = e4[j];
    }
}

// ---- K1: scores + row/col argmax.  lane = code, thread-tile = 16 tokens ----
// grid (1024 token-tiles of 64, 4 code-tiles of 256), block 256.
__global__ __launch_bounds__(256, 4) void k_scores(
    const float* __restrict__ z, const float* __restrict__ eq,
    const float* __restrict__ en2, const float* __restrict__ nzn2,
    unsigned long long* __restrict__ wsrow,
    unsigned long long* __restrict__ wscol) {
    const int t    = threadIdx.x;
    const int tile = blockIdx.x;            // 64 tokens: n0 = tile*64
    const int b    = tile >> 6;
    const int hw0  = (tile & 63) << 6;
    const int code = blockIdx.y * 256 + t;  // this thread's code

    __shared__ float tile_d[256 * 17];          // [thread(code)][token] padded
    __shared__ unsigned long long kbuf[16][16]; // [chunk][token]

    const float en2v = en2[code];
    const float4* eq4 = reinterpret_cast<const float4*>(eq);

    float cbv = -3.4e38f;   // column (per-code) running best over 64 tokens
    int   cbn = 0;

#pragma unroll 1
    for (int p = 0; p < 4; ++p) {
        const int hw = hw0 + p * 16;            // this pass's 16 tokens
        const float* zb  = z + (size_t)b * 262144 + hw;     // + c*4096 + tt
        const float* nzp = nzn2 + (size_t)tile * 64 + p * 16;

        float acc[16][4];
#pragma unroll
        for (int i = 0; i < 16; ++i)
#pragma unroll
            for (int m = 0; m < 4; ++m) acc[i][m] = 0.f;

        // K-loop: j outermost => chain m accumulates d = m,m+4,...,m+60
        // in ascending order — BIT-IDENTICAL to the blessed 4-chain dot.
#pragma unroll
        for (int j = 0; j < 16; ++j) {
            const float4 e4 = eq4[(size_t)j * 1024 + code];  // per-lane VGPR
            const float ec[4] = {e4.x, e4.y, e4.z, e4.w};
#pragma unroll
            for (int m = 0; m < 4; ++m) {
                const float* zr = zb + (size_t)(4 * j + m) * 4096;  // uniform
#pragma unroll
                for (int tt = 0; tt < 16; ++tt)
                    acc[tt][m] = fmaf(ec[m], zr[tt], acc[tt][m]);   // s_load op
            }
        }

        // epilogue: dots, compose, column-best, stash for row reduce
#pragma unroll
        for (int tt = 0; tt < 16; ++tt) {
            float dot = (acc[tt][0] + acc[tt][1]) + (acc[tt][2] + acc[tt][3]);
            float d = __fadd_rn(__fsub_rn(nzp[tt], en2v), 2.0f * dot);
            if (d > cbv) { cbv = d; cbn = tile * 64 + p * 16 + tt; } // asc token
            tile_d[t * 17 + tt] = d;     // bank (17t+tt)%32: 2-way, free
        }
        __syncthreads();

        // row argmax stage 1: thread (tok=t&15, chunk=t>>4) scans 16 codes asc
        {
            const int tok = t & 15, chunk = t >> 4;
            float bv = tile_d[(chunk * 16) * 17 + tok];
            int   bc = 0;
#pragma unroll
            for (int i = 1; i < 16; ++i) {
                float v = tile_d[(chunk * 16 + i) * 17 + tok];
                if (v > bv) { bv = v; bc = i; }          // strict > = first idx
            }
            int kwin = blockIdx.y * 256 + chunk * 16 + bc;
            kbuf[chunk][tok] =
                ((unsigned long long)f32_ord(bv) << 32) |
                (unsigned long long)(unsigned int)(~(unsigned int)kwin);
        }
        __syncthreads();
        // stage 2: merge 16 chunk keys (ties -> larger ~k = smaller k)
        if (t < 16) {
            unsigned long long mk = kbuf[0][t];
#pragma unroll
            for (int i = 1; i < 16; ++i) {
                unsigned long long o = kbuf[i][t];
                mk = (o > mk) ? o : mk;
            }
            atomicMax(&wsrow[(size_t)tile * 64 + p * 16 + t], mk);
        }
        __syncthreads();   // tile_d reused next pass
    }

    unsigned long long ck =
        ((unsigned long long)f32_ord(cbv) << 32) |
        (unsigned long long)(unsigned int)(~(unsigned int)cbn);
    atomicMax(&wscol[code], ck);
}

// ---- K2: per-token outputs: z_q, indices, hist, loss ----
__global__ __launch_bounds__(256) void k_tokens(
    const float* __restrict__ z, const float* __restrict__ emb,
    const unsigned long long* __restrict__ wsrow,
    unsigned int* __restrict__ counts, double* __restrict__ loss_acc,
    float* __restrict__ out_zq, float* __restrict__ out_idx) {
    const int n  = blockIdx.x * 256 + threadIdx.x;
    const int b  = n >> 12;
    const int hw = n & 4095;

    unsigned long long key = wsrow[n];
    int idx = (int)(~(unsigned int)(key & 0xFFFFFFFFull));
    out_idx[n] = (float)idx;
    atomicAdd(&counts[idx], 1u);

    const float* zp = z + (size_t)b * 262144 + hw;
    float*       op = out_zq + (size_t)b * 262144 + hw;
    const float4* ep4 = reinterpret_cast<const float4*>(emb) + (size_t)idx * 16;

    double ls = 0.0;
#pragma unroll
    for (int j = 0; j < 16; ++j) {
        float4 eqv = ep4[j];
        float e4[4] = {eqv.x, eqv.y, eqv.z, eqv.w};
#pragma unroll
        for (int cc = 0; cc < 4; ++cc) {
            int c = 4 * j + cc;
            float zc   = zp[(size_t)c * 4096];
            float diff = __fsub_rn(e4[cc], zc);          // fl(z_q - zc)
            float sq   = __fmul_rn(diff, diff);
            ls += (double)sq;
            op[(size_t)c * 4096] = __fadd_rn(zc, diff);  // zc + fl(z_q - zc)
        }
    }

    __shared__ double sred[256];
    sred[threadIdx.x] = ls;
    __syncthreads();
    for (int st = 128; st; st >>= 1) {
        if (threadIdx.x < st) sred[threadIdx.x] += sred[threadIdx.x + st];
        __syncthreads();
    }
    if (threadIdx.x == 0) atomicAdd(loss_acc, sred[0]);
}

// ---- K3: fused scalars (block 256) + new embedding (blocks 0..255) ----
__global__ __launch_bounds__(256) void k_post(
    const float* __restrict__ z, const float* __restrict__ emb,
    const float* __restrict__ embed_prob,
    const unsigned long long* __restrict__ wscol,
    const unsigned int* __restrict__ counts,
    const double* __restrict__ loss_acc,
    float* __restrict__ out_loss, float* __restrict__ out_perp,
    float* __restrict__ out_newemb, float* __restrict__ out_prob) {
    const int t = threadIdx.x;
    if (blockIdx.x == 256) {
        double s = 0.0;
        for (int j = 0; j < 4; ++j) {
            int k = t + j * 256;
            float avg  = (float)counts[k] * (1.0f / 65536.0f);
            float pnew = __fadd_rn(__fmul_rn(embed_prob[k], 0.99f),
                                   __fmul_rn(0.01f, avg));
            out_prob[k] = pnew;
            s += (double)__fmul_rn(avg, logf(__fadd_rn(avg, 1e-10f)));
        }
        __shared__ double red[256];
        red[t] = s;
        __syncthreads();
        for (int st = 128; st; st >>= 1) {
            if (t < st) red[t] += red[t + st];
            __syncthreads();
        }
        if (t == 0) {
            out_perp[0] = expf(-(float)red[0]);
            double lm = loss_acc[0] / 4194304.0;
            float  m  = (float)lm;
            out_loss[0] = __fadd_rn(__fmul_rn(0.25f, m), m);  // BETA*m + m
        }
        return;
    }
    const int k = blockIdx.x * 4 + (t >> 6);
    const int c = t & 63;

    float avg  = (float)counts[k] * (1.0f / 65536.0f);
    float pnew = __fadd_rn(__fmul_rn(embed_prob[k], 0.99f),
                           __fmul_rn(0.01f, avg));
    float tt = __fdiv_rn(__fmul_rn(__fmul_rn(pnew, 1024.0f), 10.0f), 0.01f);
    float dk = expf(__fsub_rn(-tt, 1e-3f));
    float omd = __fsub_rn(1.0f, dk);

    unsigned long long ck = wscol[k];
    int cn  = (int)(~(unsigned int)(ck & 0xFFFFFFFFull));
    int cb  = cn >> 12;
    int chw = cn & 4095;

    float rf = z[(size_t)cb * 262144 + (size_t)c * 4096 + chw];
    float e  = emb[(size_t)k * 64 + c];
    out_newemb[(size_t)k * 64 + c] =
        __fadd_rn(__fmul_rn(e, omd), __fmul_rn(rf, dk));
}

extern "C" void kernel_launch(void* const* d_in, const int* in_sizes, int n_in,
                              void* d_out, int out_size, void* d_ws, size_t ws_size,
                              hipStream_t stream) {
    const float* z    = (const float*)d_in[0];   // 16*64*64*64
    const float* emb  = (const float*)d_in[1];   // 1024*64
    const float* prob = (const float*)d_in[2];   // 1024

    float* out        = (float*)d_out;
    float* out_zq     = out;                 // 4194304
    float* out_loss   = out + 4194304;       // 1
    float* out_perp   = out + 4194305;       // 1
    float* out_newemb = out + 4194306;       // 65536
    float* out_prob   = out + 4259842;       // 1024
    float* out_idx    = out + 4260866;       // 65536

    char* ws = (char*)d_ws;
    unsigned long long* wsrow = (unsigned long long*)(ws + WS_ROW);
    unsigned long long* wscol = (unsigned long long*)(ws + WS_COL);
    unsigned int*       cnts  = (unsigned int*)(ws + WS_CNT);
    double*             lacc  = (double*)(ws + WS_LOSS);
    float*              en2   = (float*)(ws + WS_EN2);
    float*              nzn2  = (float*)(ws + WS_NZN2);
    float*              eqb   = (float*)(ws + WS_EQ);

    hipMemsetAsync(d_ws, 0, WS_CLEAR, stream);

    hipLaunchKernelGGL(k_prep, dim3(264), dim3(256), 0, stream,
                       z, emb, nzn2, en2, eqb);
    hipLaunchKernelGGL(k_scores, dim3(1024, 4), dim3(256), 0, stream,
                       z, eqb, en2, nzn2, wsrow, wscol);
    hipLaunchKernelGGL(k_tokens, dim3(256), dim3(256), 0, stream,
                       z, emb, wsrow, cnts, lacc, out_zq, out_idx);
    hipLaunchKernelGGL(k_post, dim3(257), dim3(256), 0, stream,
                       z, emb, prob, wscol, cnts, lacc,
                       out_loss, out_perp, out_newemb, out_prob);
}